// Round 27
// baseline (87.460 us; speedup 1.0000x reference)
//
#include <hip/hip_runtime.h>
#include <hip/hip_bf16.h>

#define B_ 8
#define C_ 2048
#define L_ 256
#define E_ 768
#define H_ 4
#define D_ 64
#define M_ (B_*C_)   // 16384 rows

typedef __attribute__((ext_vector_type(8))) short short8v;   // 8 bf16 (4 VGPR) MFMA A/B frag
typedef __attribute__((ext_vector_type(4))) short short4v;   // 8B packed store
typedef __attribute__((ext_vector_type(4))) float f32x4;     // MFMA C/D frag
typedef __attribute__((ext_vector_type(4))) unsigned uint4v;

__device__ __forceinline__ short f2bf(float f) {             // f32 -> bf16 RNE
  union { float f; unsigned u; } v; v.f = f;
  unsigned r = v.u + 0x7FFFu + ((v.u >> 16) & 1u);
  return (short)(r >> 16);
}
// two f32 -> packed bf16x2 in one VALU op (gfx950; no builtin, m240)
__device__ __forceinline__ unsigned cvtpk(float a, float b) {
  unsigned r;
  asm("v_cvt_pk_bf16_f32 %0, %1, %2" : "=v"(r) : "v"(a), "v"(b));
  return r;
}
__device__ __forceinline__ float exp2x(float x) {            // 2^x, single v_exp_f32
  float r;
  asm("v_exp_f32 %0, %1" : "=v"(r) : "v"(x));
  return r;
}

// async global->LDS, 16B per lane; LDS dest = uniform base + lane*16 (m104)
__device__ __forceinline__ void gll16(const void* g, void* l) {
  __builtin_amdgcn_global_load_lds(
      (const __attribute__((address_space(1))) unsigned int*)g,
      (__attribute__((address_space(3))) unsigned int*)l, 16, 0, 0);
}

// ---- prep: W1 f32 [256][768] and W2 f32 [256][256] -> bf16 [N][K] ----
__global__ __launch_bounds__(256) void transpose_w_kernel(
    const float* __restrict__ W1, short* __restrict__ W1t,
    const float* __restrict__ W2, short* __restrict__ W2t) {
  __shared__ float ld[32][33];
  const int isW1 = blockIdx.y < 24;
  const float* W = isW1 ? W1 : W2;
  short* Wt = isW1 ? W1t : W2t;
  const int N = isW1 ? E_ : L_;
  const int k0 = blockIdx.x * 32, n0 = (isW1 ? blockIdx.y : blockIdx.y - 24) * 32;
  const int tx = threadIdx.x & 31, ty = threadIdx.x >> 5;
  #pragma unroll
  for (int j = 0; j < 4; ++j)
    ld[ty + j*8][tx] = W[(size_t)(k0 + ty + j*8) * N + n0 + tx];
  __syncthreads();
  const int r  = threadIdx.x >> 3;
  const int c0 = (threadIdx.x & 7) * 4;
  short4v o;
  o[0]=f2bf(ld[c0+0][r]); o[1]=f2bf(ld[c0+1][r]);
  o[2]=f2bf(ld[c0+2][r]); o[3]=f2bf(ld[c0+3][r]);
  *(short4v*)(Wt + (size_t)(n0 + r) * 256 + k0 + c0) = o;
}

// ---- GEMM1 + LN1 fused (R25-proven): BM=64, Bs double-buffered with
//      counted vmcnt(6); coalesced Q/K epilogue via per-wave LDS transpose. ----
__global__ __launch_bounds__(512, 2) void gemm1_ln_fused_kernel(
    const float* __restrict__ x, const short* __restrict__ W1t,
    const float* __restrict__ b1, const float* __restrict__ g1,
    const float* __restrict__ be1,
    short* __restrict__ Qg, short* __restrict__ Kg, short* __restrict__ Vtg) {
  __shared__ short As[64*264];        // 33.8 KB
  __shared__ short Bs[2][24576];      // 2 x 48 KB per-round B tiles (chunk-swizzled)
  __shared__ short tbuf[8][64][24];   // 24.6 KB per-wave transpose tile
  __shared__ float2 red[8][64];       // 4 KB
  __shared__ float mu_s[64], rs_s[64];
  const int tid = threadIdx.x;
  const int w = tid >> 6, l = tid & 63, lo = l & 15, hi = l >> 4;
  const int m0 = blockIdx.x * 64;
  const int b = m0 >> 11, c0 = m0 & (C_ - 1);
  const int nbase = w * 96;

  // stage A: 64 rows x 256 cols, two 32-row halves
  #pragma unroll
  for (int half = 0; half < 2; ++half) {
    const int row = (tid >> 4) + half * 32, cc = (tid & 15) * 16;
    const float* ap = x + (size_t)(m0 + row) * 256 + cc;
    float4 a0 = ((const float4*)ap)[0], a1 = ((const float4*)ap)[1];
    float4 a2 = ((const float4*)ap)[2], a3 = ((const float4*)ap)[3];
    uint4 p0, p1;
    p0.x = cvtpk(a0.x,a0.y); p0.y = cvtpk(a0.z,a0.w);
    p0.z = cvtpk(a1.x,a1.y); p0.w = cvtpk(a1.z,a1.w);
    p1.x = cvtpk(a2.x,a2.y); p1.y = cvtpk(a2.z,a2.w);
    p1.z = cvtpk(a3.x,a3.y); p1.w = cvtpk(a3.z,a3.w);
    *(uint4*)&As[row*264 + cc]     = p0;
    *(uint4*)&As[row*264 + cc + 8] = p1;
  }

  f32x4 acc[4][6];
  #pragma unroll
  for (int m = 0; m < 4; ++m)
    #pragma unroll
    for (int n = 0; n < 6; ++n) acc[m][n] = (f32x4){0.f,0.f,0.f,0.f};

  // B staging geometry (as R23): issue i covers W1t rows i*128..+127
  const int srowl = l >> 2;
  const int schunk = ((l & 3) ^ (srowl & 3)) << 3;

  // prologue: stage round 0 -> buf 0
  #pragma unroll
  for (int i = 0; i < 6; ++i) {
    const short* src = W1t + (size_t)(i*128 + w*16 + srowl) * 256 + schunk;
    gll16(src, &Bs[0][i*4096 + w*512]);
  }
  __syncthreads();                     // As staged (also pre-loop sync)

  for (int r8 = 0; r8 < 8; ++r8) {
    if (r8) __builtin_amdgcn_s_barrier();   // compute(r8-1) done: buf[(r8+1)&1] free
    if (r8 < 7) {                            // stage round r8+1 -> other buffer
      #pragma unroll
      for (int i = 0; i < 6; ++i) {
        const short* src = W1t + (size_t)(i*128 + w*16 + srowl) * 256
                         + (r8+1)*32 + schunk;
        gll16(src, &Bs[(r8+1)&1][i*4096 + w*512]);
      }
      asm volatile("s_waitcnt vmcnt(6)" ::: "memory");   // round r8's 6 landed
    } else {
      asm volatile("s_waitcnt vmcnt(0)" ::: "memory");
    }
    __builtin_amdgcn_s_barrier();            // all waves' round-r8 DMA complete
    const short* Bc = &Bs[r8&1][0];

    short8v af[4];
    #pragma unroll
    for (int m = 0; m < 4; ++m)
      af[m] = *(short8v*)&As[(m*16 + lo)*264 + r8*32 + hi*8];
    #pragma unroll
    for (int n = 0; n < 6; ++n) {
      const int row = nbase + n*16 + lo;
      short8v bfn = *(const short8v*)&Bc[row*32 + ((hi ^ (lo & 3)) << 3)];
      #pragma unroll
      for (int m = 0; m < 4; ++m)
        acc[m][n] = __builtin_amdgcn_mfma_f32_16x16x32_bf16(af[m], bfn, acc[m][n], 0,0,0);
    }
  }

  float bb[6], ggv[6], eev[6];
  #pragma unroll
  for (int n = 0; n < 6; ++n) {
    int col = nbase + n*16 + lo;
    bb[n] = b1[col]; ggv[n] = g1[col]; eev[n] = be1[col];
  }
  #pragma unroll
  for (int m = 0; m < 4; ++m)
    #pragma unroll
    for (int r = 0; r < 4; ++r) {
      float s = 0.f, s2 = 0.f;
      #pragma unroll
      for (int n = 0; n < 6; ++n) {
        float v = acc[m][n][r] + bb[n];
        acc[m][n][r] = v;
        s += v; s2 += v*v;
      }
      #pragma unroll
      for (int off = 1; off < 16; off <<= 1) {
        s  += __shfl_xor(s, off);
        s2 += __shfl_xor(s2, off);
      }
      if (lo == 0) red[w][m*16 + hi*4 + r] = make_float2(s, s2);
    }
  __syncthreads();
  if (tid < 64) {
    float s = 0.f, s2 = 0.f;
    #pragma unroll
    for (int wv = 0; wv < 8; ++wv) { s += red[wv][tid].x; s2 += red[wv][tid].y; }
    float mu = s * (1.f / E_);
    float var = s2 * (1.f / E_) - mu * mu;
    mu_s[tid] = mu;
    rs_s[tid] = rsqrtf(var + 1e-5f);
  }
  __syncthreads();

  const float qs = 0.18033688011f;    // 0.125 * log2(e)
  float muv[4][4], rsv[4][4];
  #pragma unroll
  for (int m = 0; m < 4; ++m)
    #pragma unroll
    for (int r = 0; r < 4; ++r) {
      int row = m*16 + hi*4 + r;
      muv[m][r] = mu_s[row]; rsv[m][r] = rs_s[row];
    }

  #pragma unroll
  for (int n = 0; n < 6; ++n) {
    const int e0b = nbase + n*16;              // tile base (wave-uniform)
    if (e0b < 512) {                           // Q or K: LDS transpose -> 16B stores
      const float qscale = (e0b < 256) ? qs : 1.f;
      #pragma unroll
      for (int m = 0; m < 4; ++m)
        #pragma unroll
        for (int r = 0; r < 4; ++r) {
          float v = (acc[m][n][r] - muv[m][r]) * rsv[m][r] * ggv[n] + eev[n];
          tbuf[w][m*16 + hi*4 + r][lo] = f2bf(v * qscale);
        }
      // same-wave RAW on tbuf: in-order DS + compiler lgkmcnt
      #pragma unroll
      for (int half = 0; half < 2; ++half) {
        const int trow = (l >> 1) + half * 32, tc = (l & 1) * 8;
        short8v tv = *(short8v*)&tbuf[w][trow][tc];
        const int c = c0 + trow;
        if (e0b < 256) {                       // Q: d-contiguous 16B
          const int h = e0b >> 6, d0 = (e0b & 63) + tc;
          *(short8v*)(Qg + ((size_t)(b*H_ + h) * C_ + c) * D_ + d0) = tv;
        } else {                               // K: full swizzle chunk pair (16B)
          const int eb = e0b - 256, h = eb >> 6, d0 = (eb & 63) + tc;
          int a5 = c & 31;
          int p5 = (((a5 >> 2) & 1) << 4) | (((a5 >> 3) & 3) << 2) | (a5 & 3);
          int cs = (c & ~31) | p5;
          *(short8v*)(Kg + ((size_t)(b*H_ + h) * C_ + cs) * D_
                        + (((d0 >> 3) ^ (cs & 7)) << 3)) = tv;
        }
      }
    } else {                                   // Vt: 8B-contiguous, direct
      const int e0 = e0b + lo;
      const int eb = e0 - 512, h = eb >> 6, d = eb & 63;
      #pragma unroll
      for (int m = 0; m < 4; ++m) {
        short4v pk;
        #pragma unroll
        for (int r = 0; r < 4; ++r)
          pk[r] = f2bf((acc[m][n][r] - muv[m][r]) * rsv[m][r] * ggv[n] + eev[n]);
        const int c = c0 + m*16 + hi*4;
        size_t off = ((size_t)(b*H_ + h) * D_ + d) * C_ + (c & ~63)
                   + ((((c & 63) >> 3) ^ (d & 7)) << 3) + (c & 7);
        *(short4v*)(Vtg + off) = pk;
      }
    }
  }
}

// ---- MFMA flash attention. R26: QUAD-buffered K/V, 2 K-tiles per barrier
//      (halves the 32 per-kt barrier rounds; 36-MFMA runs between barriers).
//      R8's failure mode (P-LDS reuse fencing) is gone: P is in registers
//      (R17 key-permutation). Fixed-ref softmax; l via ones-MFMA. ----
__global__ __launch_bounds__(512, 4) void attn_mfma_kernel(
    const short* __restrict__ Qg, const short* __restrict__ Kg,
    const short* __restrict__ Vtg, short* __restrict__ ob) {
  __shared__ short Ks[4][4096];     // 32 KB
  __shared__ short Vs[4][4096];     // 32 KB -> 64 KB total, 2 blocks/CU
  const int tid = threadIdx.x;
  const int w  = tid >> 6;
  const int l  = tid & 63, lo = l & 15, hi = l >> 4;
  const int sw = lo & 7;
  const int bh = blockIdx.x, qt = blockIdx.y;
  const size_t hd = (size_t)bh * (C_ * D_);
  const int q0 = qt * 128 + w * 16;

  const short8v bq0 = *(const short8v*)(Qg + hd + (size_t)(q0+lo)*D_ + hi*8);
  const short8v bq1 = *(const short8v*)(Qg + hd + (size_t)(q0+lo)*D_ + 32 + hi*8);

  short8v ones;
  #pragma unroll
  for (int j = 0; j < 8; ++j) ones[j] = (short)0x3F80;

  const short* Ktile = Kg + hd;
  const short* Vrow  = Vtg + hd;
  const int kOff = w*512 + l*8;
  const size_t vOff = (size_t)(w*8 + (l>>3)) * C_ + (l&7)*8;

  f32x4 Oacc[4] = {{0,0,0,0},{0,0,0,0},{0,0,0,0},{0,0,0,0}};
  f32x4 Lacc = {0.f, 0.f, 0.f, 0.f};
  const f32x4 zero4 = {0.f, 0.f, 0.f, 0.f};

  // prologue: stage tiles 0 -> buf0, 1 -> buf1
  gll16(Ktile + kOff,        &Ks[0][w*512]);
  gll16(Vrow + vOff,         &Vs[0][w*512]);
  gll16(Ktile + 4096 + kOff, &Ks[1][w*512]);
  gll16(Vrow + 64 + vOff,    &Vs[1][w*512]);

  for (int kt = 0; kt < 32; kt += 2) {
    asm volatile("s_waitcnt vmcnt(0)" ::: "memory");  // tiles kt,kt+1 landed
    __builtin_amdgcn_s_barrier();       // all waves done with bufs (kt+2)&3,(kt+3)&3
    if (kt < 30) {                       // stage kt+2, kt+3 (read 2 iters ago)
      const short* k2 = Ktile + (size_t)(kt+2) * 4096;
      const short* v2 = Vrow  + (size_t)(kt+2) * 64;
      gll16(k2 + kOff,        &Ks[(kt+2)&3][w*512]);
      gll16(v2 + vOff,        &Vs[(kt+2)&3][w*512]);
      gll16(k2 + 4096 + kOff, &Ks[(kt+3)&3][w*512]);
      gll16(v2 + 64 + vOff,   &Vs[(kt+3)&3][w*512]);
    }

    #pragma unroll
    for (int sub = 0; sub < 2; ++sub) {
      const short* Kc = &Ks[(kt+sub)&3][0];
      const short* Vc = &Vs[(kt+sub)&3][0];

      f32x4 st[4];
      __builtin_amdgcn_s_setprio(1);
      #pragma unroll
      for (int mt = 0; mt < 4; ++mt) {
        short8v ka = *(const short8v*)&Kc[(mt*16 + lo)*64 + ((hi ^ sw) << 3)];
        short8v kb = *(const short8v*)&Kc[(mt*16 + lo)*64 + (((4 + hi) ^ sw) << 3)];
        f32x4 z = __builtin_amdgcn_mfma_f32_16x16x32_bf16(ka, bq0, zero4, 0, 0, 0);
        st[mt]  = __builtin_amdgcn_mfma_f32_16x16x32_bf16(kb, bq1, z, 0, 0, 0);
      }
      __builtin_amdgcn_s_setprio(0);

      float ps[16];
      #pragma unroll
      for (int mt = 0; mt < 4; ++mt)
        #pragma unroll
        for (int r = 0; r < 4; ++r)
          ps[mt*4 + r] = exp2x(st[mt][r]);
      uint4v up0 = { cvtpk(ps[0], ps[1]),  cvtpk(ps[2], ps[3]),
                     cvtpk(ps[4], ps[5]),  cvtpk(ps[6], ps[7]) };
      uint4v up1 = { cvtpk(ps[8], ps[9]),  cvtpk(ps[10], ps[11]),
                     cvtpk(ps[12], ps[13]), cvtpk(ps[14], ps[15]) };
      short8v pa0 = __builtin_bit_cast(short8v, up0);
      short8v pa1 = __builtin_bit_cast(short8v, up1);

      __builtin_amdgcn_s_setprio(1);
      Lacc = __builtin_amdgcn_mfma_f32_16x16x32_bf16(pa0, ones, Lacc, 0, 0, 0);
      Lacc = __builtin_amdgcn_mfma_f32_16x16x32_bf16(pa1, ones, Lacc, 0, 0, 0);
      #pragma unroll
      for (int nt = 0; nt < 4; ++nt) {
        short8v vb0 = *(const short8v*)&Vc[(nt*16 + lo)*64 + ((hi ^ sw) << 3)];
        short8v vb1 = *(const short8v*)&Vc[(nt*16 + lo)*64 + (((4 + hi) ^ sw) << 3)];
        Oacc[nt] = __builtin_amdgcn_mfma_f32_16x16x32_bf16(pa0, vb0, Oacc[nt], 0,0,0);
        Oacc[nt] = __builtin_amdgcn_mfma_f32_16x16x32_bf16(pa1, vb1, Oacc[nt], 0,0,0);
      }
      __builtin_amdgcn_s_setprio(0);
    }
  }

  float invL[4];
  #pragma unroll
  for (int r = 0; r < 4; ++r) invL[r] = 1.f / Lacc[r];
  const int b = bh >> 2, h = bh & 3;
  short* obp = ob + ((size_t)b * C_ + q0) * L_ + h * D_;
  #pragma unroll
  for (int nt = 0; nt < 4; ++nt)
    #pragma unroll
    for (int r = 0; r < 4; ++r)
      obp[(hi*4 + r) * L_ + nt*16 + lo] = f2bf(Oacc[nt][r] * invL[r]);
}

// ---- GEMM2 + LN2 + residual, fused (R13-proven). ----
__global__ __launch_bounds__(256, 4) void gemm2_ln_mfma_kernel(
    const short* __restrict__ ob, const short* __restrict__ W2t,
    const float* __restrict__ b2, const float* __restrict__ g2,
    const float* __restrict__ be2, const float* __restrict__ x,
    float* __restrict__ out) {
  __shared__ short As[32*264];
  __shared__ float2 red[4][32];
  __shared__ float mu_s[32], rs_s[32];
  const int tid = threadIdx.x;
  const int w = tid >> 6, l = tid & 63, lo = l & 15, hi = l >> 4;
  const int m0 = blockIdx.x * 32;
  const int nbase = w * 64;

  #pragma unroll
  for (int i = 0; i < 4; ++i) {
    int id = tid + i * 256;
    int row = id >> 5, c8 = (id & 31) * 8;
    *(short8v*)&As[row*264 + c8] =
        *(const short8v*)(ob + (size_t)(m0 + row) * 256 + c8);
  }
  __syncthreads();

  f32x4 acc[2][4];
  #pragma unroll
  for (int m = 0; m < 2; ++m)
    #pragma unroll
    for (int n = 0; n < 4; ++n) acc[m][n] = (f32x4){0.f,0.f,0.f,0.f};

  #pragma unroll
  for (int kt = 0; kt < 4; ++kt)
    #pragma unroll
    for (int kk = 0; kk < 2; ++kk) {
      short8v bf[4];
      #pragma unroll
      for (int n = 0; n < 4; ++n)
        bf[n] = *(const short8v*)(W2t + (size_t)(nbase + n*16 + lo) * 256
                                     + kt*64 + kk*32 + hi*8);
      short8v af0 = *(short8v*)&As[lo*264      + kt*64 + kk*32 + hi*8];
      short8v af1 = *(short8v*)&As[(16+lo)*264 + kt*64 + kk*32 + hi*8];
      #pragma unroll
      for (int n = 0; n < 4; ++n) {
        acc[0][n] = __builtin_amdgcn_mfma_f32_16x16x32_bf16(af0, bf[n], acc[0][n], 0,0,0);
        acc[1][n] = __builtin_amdgcn_mfma_f32_16x16x32_bf16(af1, bf[n], acc[1][n], 0,0,0);
      }
    }

  float bb[4], gg[4], ee[4];
  #pragma unroll
  for (int n = 0; n < 4; ++n) {
    int col = nbase + n*16 + lo;
    bb[n] = b2[col]; gg[n] = g2[col]; ee[n] = be2[col];
  }
  #pragma unroll
  for (int m = 0; m < 2; ++m)
    #pragma unroll
    for (int r = 0; r < 4; ++r) {
      float s = 0.f, s2 = 0.f;
      #pragma unroll
      for (int n = 0; n < 4; ++n) {
        float v = acc[m][n][r] + bb[n];
        acc[m][n][r] = v;
        s += v; s2 += v*v;
      }
      #pragma unroll
      for (int off = 1; off < 16; off <<= 1) {
        s  += __shfl_xor(s, off);
        s2 += __shfl_xor(s2, off);
      }
      if (lo == 0) red[w][m*16 + hi*4 + r] = make_float2(s, s2);
    }
  __syncthreads();
  if (tid < 32) {
    float s = 0.f, s2 = 0.f;
    #pragma unroll
    for (int wv = 0; wv < 4; ++wv) { s += red[wv][tid].x; s2 += red[wv][tid].y; }
    float mu = s * (1.f / L_);
    float var = s2 * (1.f / L_) - mu * mu;
    mu_s[tid] = mu;
    rs_s[tid] = rsqrtf(var + 1e-5f);
  }
  __syncthreads();

  #pragma unroll
  for (int m = 0; m < 2; ++m) {
    float mu4[4], rs4[4];
    #pragma unroll
    for (int r = 0; r < 4; ++r) {
      int row = m*16 + hi*4 + r;
      mu4[r] = mu_s[row]; rs4[r] = rs_s[row];
    }
    #pragma unroll
    for (int r = 0; r < 4; ++r) {
      const int grow = m0 + m*16 + hi*4 + r;
      const float* xr = x + (size_t)grow * L_ + nbase;
      float* orow = out + (size_t)grow * L_ + nbase;
      #pragma unroll
      for (int n = 0; n < 4; ++n)
        orow[n*16 + lo] = (acc[m][n][r] - mu4[r]) * rs4[r] * gg[n] + ee[n]
                        + xr[n*16 + lo];
    }
  }
}

extern "C" void kernel_launch(void* const* d_in, const int* in_sizes, int n_in,
                              void* d_out, int out_size, void* d_ws, size_t ws_size,
                              hipStream_t stream) {
  const float* x   = (const float*)d_in[0];
  const float* W1  = (const float*)d_in[1];
  const float* b1  = (const float*)d_in[2];
  const float* g1  = (const float*)d_in[3];
  const float* be1 = (const float*)d_in[4];
  const float* W2  = (const float*)d_in[5];
  const float* b2  = (const float*)d_in[6];
  const float* g2  = (const float*)d_in[7];
  const float* be2 = (const float*)d_in[8];
  float* out = (float*)d_out;

  const size_t HDSZ = (size_t)B_ * H_ * C_ * D_;   // 4,194,304
  short* W1t = (short*)d_ws;          // [768][256] bf16
  short* W2t = W1t + (size_t)L_ * E_; // [256][256] bf16
  short* Qg  = W2t + (size_t)L_ * L_; // [bh][c][64] (pre-scaled, log2 domain)
  short* Kg  = Qg  + HDSZ;            // [bh][c][64] key-permuted + swizzled
  short* Vtg = Kg  + HDSZ;            // [bh][64][c] swizzled
  short* obm = Vtg + HDSZ;            // [M][256] bf16

  transpose_w_kernel<<<dim3(8, 32), 256, 0, stream>>>(W1, W1t, W2, W2t);
  gemm1_ln_fused_kernel<<<M_ / 64, 512, 0, stream>>>(x, W1t, b1, g1, be1, Qg, Kg, Vtg);
  attn_mfma_kernel<<<dim3(32, C_ / 128), 512, 0, stream>>>(Qg, Kg, Vtg, obm);
  gemm2_ln_mfma_kernel<<<M_ / 32, 256, 0, stream>>>(obm, W2t, b2, g2, be2, x, out);
}

// Round 28
// 87.359 us; speedup vs baseline: 1.0012x; 1.0012x over previous
//
#include <hip/hip_runtime.h>
#include <hip/hip_bf16.h>

#define B_ 8
#define C_ 2048
#define L_ 256
#define E_ 768
#define H_ 4
#define D_ 64
#define M_ (B_*C_)   // 16384 rows

typedef __attribute__((ext_vector_type(8))) short short8v;   // 8 bf16 (4 VGPR) MFMA A/B frag
typedef __attribute__((ext_vector_type(4))) short short4v;   // 8B packed store
typedef __attribute__((ext_vector_type(4))) float f32x4;     // MFMA C/D frag
typedef __attribute__((ext_vector_type(4))) unsigned uint4v;

__device__ __forceinline__ short f2bf(float f) {             // f32 -> bf16 RNE
  union { float f; unsigned u; } v; v.f = f;
  unsigned r = v.u + 0x7FFFu + ((v.u >> 16) & 1u);
  return (short)(r >> 16);
}
// two f32 -> packed bf16x2 in one VALU op (gfx950; no builtin, m240)
__device__ __forceinline__ unsigned cvtpk(float a, float b) {
  unsigned r;
  asm("v_cvt_pk_bf16_f32 %0, %1, %2" : "=v"(r) : "v"(a), "v"(b));
  return r;
}
__device__ __forceinline__ float exp2x(float x) {            // 2^x, single v_exp_f32
  float r;
  asm("v_exp_f32 %0, %1" : "=v"(r) : "v"(x));
  return r;
}

// async global->LDS, 16B per lane; LDS dest = uniform base + lane*16 (m104)
__device__ __forceinline__ void gll16(const void* g, void* l) {
  __builtin_amdgcn_global_load_lds(
      (const __attribute__((address_space(1))) unsigned int*)g,
      (__attribute__((address_space(3))) unsigned int*)l, 16, 0, 0);
}

// ---- prep: W1 f32 [256][768] and W2 f32 [256][256] -> bf16 [N][K] ----
__global__ __launch_bounds__(256) void transpose_w_kernel(
    const float* __restrict__ W1, short* __restrict__ W1t,
    const float* __restrict__ W2, short* __restrict__ W2t) {
  __shared__ float ld[32][33];
  const int isW1 = blockIdx.y < 24;
  const float* W = isW1 ? W1 : W2;
  short* Wt = isW1 ? W1t : W2t;
  const int N = isW1 ? E_ : L_;
  const int k0 = blockIdx.x * 32, n0 = (isW1 ? blockIdx.y : blockIdx.y - 24) * 32;
  const int tx = threadIdx.x & 31, ty = threadIdx.x >> 5;
  #pragma unroll
  for (int j = 0; j < 4; ++j)
    ld[ty + j*8][tx] = W[(size_t)(k0 + ty + j*8) * N + n0 + tx];
  __syncthreads();
  const int r  = threadIdx.x >> 3;
  const int c0 = (threadIdx.x & 7) * 4;
  short4v o;
  o[0]=f2bf(ld[c0+0][r]); o[1]=f2bf(ld[c0+1][r]);
  o[2]=f2bf(ld[c0+2][r]); o[3]=f2bf(ld[c0+3][r]);
  *(short4v*)(Wt + (size_t)(n0 + r) * 256 + k0 + c0) = o;
}

// ---- GEMM1 + LN1 fused (R25-proven): BM=64, Bs double-buffered with
//      counted vmcnt(6); coalesced Q/K epilogue via per-wave LDS transpose. ----
__global__ __launch_bounds__(512, 2) void gemm1_ln_fused_kernel(
    const float* __restrict__ x, const short* __restrict__ W1t,
    const float* __restrict__ b1, const float* __restrict__ g1,
    const float* __restrict__ be1,
    short* __restrict__ Qg, short* __restrict__ Kg, short* __restrict__ Vtg) {
  __shared__ short As[64*264];        // 33.8 KB
  __shared__ short Bs[2][24576];      // 2 x 48 KB per-round B tiles (chunk-swizzled)
  __shared__ short tbuf[8][64][24];   // 24.6 KB per-wave transpose tile
  __shared__ float2 red[8][64];       // 4 KB
  __shared__ float mu_s[64], rs_s[64];
  const int tid = threadIdx.x;
  const int w = tid >> 6, l = tid & 63, lo = l & 15, hi = l >> 4;
  const int m0 = blockIdx.x * 64;
  const int b = m0 >> 11, c0 = m0 & (C_ - 1);
  const int nbase = w * 96;

  // stage A: 64 rows x 256 cols, two 32-row halves
  #pragma unroll
  for (int half = 0; half < 2; ++half) {
    const int row = (tid >> 4) + half * 32, cc = (tid & 15) * 16;
    const float* ap = x + (size_t)(m0 + row) * 256 + cc;
    float4 a0 = ((const float4*)ap)[0], a1 = ((const float4*)ap)[1];
    float4 a2 = ((const float4*)ap)[2], a3 = ((const float4*)ap)[3];
    uint4 p0, p1;
    p0.x = cvtpk(a0.x,a0.y); p0.y = cvtpk(a0.z,a0.w);
    p0.z = cvtpk(a1.x,a1.y); p0.w = cvtpk(a1.z,a1.w);
    p1.x = cvtpk(a2.x,a2.y); p1.y = cvtpk(a2.z,a2.w);
    p1.z = cvtpk(a3.x,a3.y); p1.w = cvtpk(a3.z,a3.w);
    *(uint4*)&As[row*264 + cc]     = p0;
    *(uint4*)&As[row*264 + cc + 8] = p1;
  }

  f32x4 acc[4][6];
  #pragma unroll
  for (int m = 0; m < 4; ++m)
    #pragma unroll
    for (int n = 0; n < 6; ++n) acc[m][n] = (f32x4){0.f,0.f,0.f,0.f};

  // B staging geometry (as R23): issue i covers W1t rows i*128..+127
  const int srowl = l >> 2;
  const int schunk = ((l & 3) ^ (srowl & 3)) << 3;

  // prologue: stage round 0 -> buf 0
  #pragma unroll
  for (int i = 0; i < 6; ++i) {
    const short* src = W1t + (size_t)(i*128 + w*16 + srowl) * 256 + schunk;
    gll16(src, &Bs[0][i*4096 + w*512]);
  }
  __syncthreads();                     // As staged (also pre-loop sync)

  for (int r8 = 0; r8 < 8; ++r8) {
    if (r8) __builtin_amdgcn_s_barrier();   // compute(r8-1) done: buf[(r8+1)&1] free
    if (r8 < 7) {                            // stage round r8+1 -> other buffer
      #pragma unroll
      for (int i = 0; i < 6; ++i) {
        const short* src = W1t + (size_t)(i*128 + w*16 + srowl) * 256
                         + (r8+1)*32 + schunk;
        gll16(src, &Bs[(r8+1)&1][i*4096 + w*512]);
      }
      asm volatile("s_waitcnt vmcnt(6)" ::: "memory");   // round r8's 6 landed
    } else {
      asm volatile("s_waitcnt vmcnt(0)" ::: "memory");
    }
    __builtin_amdgcn_s_barrier();            // all waves' round-r8 DMA complete
    const short* Bc = &Bs[r8&1][0];

    short8v af[4];
    #pragma unroll
    for (int m = 0; m < 4; ++m)
      af[m] = *(short8v*)&As[(m*16 + lo)*264 + r8*32 + hi*8];
    #pragma unroll
    for (int n = 0; n < 6; ++n) {
      const int row = nbase + n*16 + lo;
      short8v bfn = *(const short8v*)&Bc[row*32 + ((hi ^ (lo & 3)) << 3)];
      #pragma unroll
      for (int m = 0; m < 4; ++m)
        acc[m][n] = __builtin_amdgcn_mfma_f32_16x16x32_bf16(af[m], bfn, acc[m][n], 0,0,0);
    }
  }

  float bb[6], ggv[6], eev[6];
  #pragma unroll
  for (int n = 0; n < 6; ++n) {
    int col = nbase + n*16 + lo;
    bb[n] = b1[col]; ggv[n] = g1[col]; eev[n] = be1[col];
  }
  #pragma unroll
  for (int m = 0; m < 4; ++m)
    #pragma unroll
    for (int r = 0; r < 4; ++r) {
      float s = 0.f, s2 = 0.f;
      #pragma unroll
      for (int n = 0; n < 6; ++n) {
        float v = acc[m][n][r] + bb[n];
        acc[m][n][r] = v;
        s += v; s2 += v*v;
      }
      #pragma unroll
      for (int off = 1; off < 16; off <<= 1) {
        s  += __shfl_xor(s, off);
        s2 += __shfl_xor(s2, off);
      }
      if (lo == 0) red[w][m*16 + hi*4 + r] = make_float2(s, s2);
    }
  __syncthreads();
  if (tid < 64) {
    float s = 0.f, s2 = 0.f;
    #pragma unroll
    for (int wv = 0; wv < 8; ++wv) { s += red[wv][tid].x; s2 += red[wv][tid].y; }
    float mu = s * (1.f / E_);
    float var = s2 * (1.f / E_) - mu * mu;
    mu_s[tid] = mu;
    rs_s[tid] = rsqrtf(var + 1e-5f);
  }
  __syncthreads();

  const float qs = 0.18033688011f;    // 0.125 * log2(e)
  float muv[4][4], rsv[4][4];
  #pragma unroll
  for (int m = 0; m < 4; ++m)
    #pragma unroll
    for (int r = 0; r < 4; ++r) {
      int row = m*16 + hi*4 + r;
      muv[m][r] = mu_s[row]; rsv[m][r] = rs_s[row];
    }

  #pragma unroll
  for (int n = 0; n < 6; ++n) {
    const int e0b = nbase + n*16;              // tile base (wave-uniform)
    if (e0b < 512) {                           // Q or K: LDS transpose -> 16B stores
      const float qscale = (e0b < 256) ? qs : 1.f;
      #pragma unroll
      for (int m = 0; m < 4; ++m)
        #pragma unroll
        for (int r = 0; r < 4; ++r) {
          float v = (acc[m][n][r] - muv[m][r]) * rsv[m][r] * ggv[n] + eev[n];
          tbuf[w][m*16 + hi*4 + r][lo] = f2bf(v * qscale);
        }
      // same-wave RAW on tbuf: in-order DS + compiler lgkmcnt
      #pragma unroll
      for (int half = 0; half < 2; ++half) {
        const int trow = (l >> 1) + half * 32, tc = (l & 1) * 8;
        short8v tv = *(short8v*)&tbuf[w][trow][tc];
        const int c = c0 + trow;
        if (e0b < 256) {                       // Q: d-contiguous 16B
          const int h = e0b >> 6, d0 = (e0b & 63) + tc;
          *(short8v*)(Qg + ((size_t)(b*H_ + h) * C_ + c) * D_ + d0) = tv;
        } else {                               // K: full swizzle chunk pair (16B)
          const int eb = e0b - 256, h = eb >> 6, d0 = (eb & 63) + tc;
          int a5 = c & 31;
          int p5 = (((a5 >> 2) & 1) << 4) | (((a5 >> 3) & 3) << 2) | (a5 & 3);
          int cs = (c & ~31) | p5;
          *(short8v*)(Kg + ((size_t)(b*H_ + h) * C_ + cs) * D_
                        + (((d0 >> 3) ^ (cs & 7)) << 3)) = tv;
        }
      }
    } else {                                   // Vt: 8B-contiguous, direct
      const int e0 = e0b + lo;
      const int eb = e0 - 512, h = eb >> 6, d = eb & 63;
      #pragma unroll
      for (int m = 0; m < 4; ++m) {
        short4v pk;
        #pragma unroll
        for (int r = 0; r < 4; ++r)
          pk[r] = f2bf((acc[m][n][r] - muv[m][r]) * rsv[m][r] * ggv[n] + eev[n]);
        const int c = c0 + m*16 + hi*4;
        size_t off = ((size_t)(b*H_ + h) * D_ + d) * C_ + (c & ~63)
                   + ((((c & 63) >> 3) ^ (d & 7)) << 3) + (c & 7);
        *(short4v*)(Vtg + off) = pk;
      }
    }
  }
}

// ---- MFMA flash attention. R27: 4 waves x 32 q-rows (two 16-row halves);
//      each K/V LDS fragment read ONCE feeds BOTH halves -> DS traffic per
//      (block,kt) halves (128->64 KB; attn measured LDS-BW-bound at 1556 cy
//      ~= the 128KB/85B/cy floor). P in registers (R17) so R11's P-LDS
//      penalty is gone; 48 KB triple-buffer -> 3 blocks/CU (12 waves). ----
__global__ __launch_bounds__(256, 3) void attn_mfma_kernel(
    const short* __restrict__ Qg, const short* __restrict__ Kg,
    const short* __restrict__ Vtg, short* __restrict__ ob) {
  __shared__ short Ks[3][4096];
  __shared__ short Vs[3][4096];
  const int tid = threadIdx.x;
  const int w  = tid >> 6;          // 0..3
  const int l  = tid & 63, lo = l & 15, hi = l >> 4;
  const int sw = lo & 7;
  const int bh = blockIdx.x, qt = blockIdx.y;
  const size_t hd = (size_t)bh * (C_ * D_);
  const int q0 = qt * 128 + w * 32;

  const short8v bqA0 = *(const short8v*)(Qg + hd + (size_t)(q0+lo)*D_ + hi*8);
  const short8v bqA1 = *(const short8v*)(Qg + hd + (size_t)(q0+lo)*D_ + 32 + hi*8);
  const short8v bqB0 = *(const short8v*)(Qg + hd + (size_t)(q0+16+lo)*D_ + hi*8);
  const short8v bqB1 = *(const short8v*)(Qg + hd + (size_t)(q0+16+lo)*D_ + 32 + hi*8);

  short8v ones;
  #pragma unroll
  for (int j = 0; j < 8; ++j) ones[j] = (short)0x3F80;

  // staging: wave w DMAs segments {2w, 2w+1} (1KB each) of K and V per tile
  const short* Ktile = Kg + hd;
  const short* Vrow  = Vtg + hd;
  const int segA = w*2, segB = segA + 1;
  const int kOffA = segA*512 + l*8, kOffB = segB*512 + l*8;
  const size_t vOffA = (size_t)(segA*8 + (l>>3)) * C_ + (l&7)*8;
  const size_t vOffB = (size_t)(segB*8 + (l>>3)) * C_ + (l&7)*8;

  f32x4 OaccA[4] = {{0,0,0,0},{0,0,0,0},{0,0,0,0},{0,0,0,0}};
  f32x4 OaccB[4] = {{0,0,0,0},{0,0,0,0},{0,0,0,0},{0,0,0,0}};
  f32x4 LaccA = {0.f,0.f,0.f,0.f}, LaccB = {0.f,0.f,0.f,0.f};
  const f32x4 zero4 = {0.f, 0.f, 0.f, 0.f};

  gll16(Ktile + kOffA, &Ks[0][segA*512]);
  gll16(Ktile + kOffB, &Ks[0][segB*512]);
  gll16(Vrow + vOffA,  &Vs[0][segA*512]);
  gll16(Vrow + vOffB,  &Vs[0][segB*512]);

  int cur = 0, nxt = 1;
  for (int kt = 0; kt < 32; ++kt) {
    asm volatile("s_waitcnt vmcnt(0)" ::: "memory");
    __builtin_amdgcn_s_barrier();        // buf[cur] full; buf[nxt] free (read kt-2)
    if (kt != 31) {
      const short* kn = Ktile + (size_t)(kt+1) * 4096;
      const short* vn = Vrow  + (size_t)(kt+1) * 64;
      gll16(kn + kOffA, &Ks[nxt][segA*512]);
      gll16(kn + kOffB, &Ks[nxt][segB*512]);
      gll16(vn + vOffA, &Vs[nxt][segA*512]);
      gll16(vn + vOffB, &Vs[nxt][segB*512]);
    }
    const short* Kc = &Ks[cur][0];
    const short* Vc = &Vs[cur][0];

    // QK^T both halves: each ka/kb read once, used twice
    f32x4 stA[4], stB[4];
    __builtin_amdgcn_s_setprio(1);
    #pragma unroll
    for (int mt = 0; mt < 4; ++mt) {
      short8v ka = *(const short8v*)&Kc[(mt*16 + lo)*64 + ((hi ^ sw) << 3)];
      short8v kb = *(const short8v*)&Kc[(mt*16 + lo)*64 + (((4 + hi) ^ sw) << 3)];
      f32x4 zA = __builtin_amdgcn_mfma_f32_16x16x32_bf16(ka, bqA0, zero4, 0, 0, 0);
      stA[mt]  = __builtin_amdgcn_mfma_f32_16x16x32_bf16(kb, bqA1, zA, 0, 0, 0);
      f32x4 zB = __builtin_amdgcn_mfma_f32_16x16x32_bf16(ka, bqB0, zero4, 0, 0, 0);
      stB[mt]  = __builtin_amdgcn_mfma_f32_16x16x32_bf16(kb, bqB1, zB, 0, 0, 0);
    }
    __builtin_amdgcn_s_setprio(0);

    // fixed-reference softmax, P packed straight into A-frags (no LDS)
    float psA[16], psB[16];
    #pragma unroll
    for (int mt = 0; mt < 4; ++mt)
      #pragma unroll
      for (int r = 0; r < 4; ++r) {
        psA[mt*4 + r] = exp2x(stA[mt][r]);
        psB[mt*4 + r] = exp2x(stB[mt][r]);
      }
    uint4v uA0 = { cvtpk(psA[0], psA[1]),  cvtpk(psA[2], psA[3]),
                   cvtpk(psA[4], psA[5]),  cvtpk(psA[6], psA[7]) };
    uint4v uA1 = { cvtpk(psA[8], psA[9]),  cvtpk(psA[10], psA[11]),
                   cvtpk(psA[12], psA[13]), cvtpk(psA[14], psA[15]) };
    uint4v uB0 = { cvtpk(psB[0], psB[1]),  cvtpk(psB[2], psB[3]),
                   cvtpk(psB[4], psB[5]),  cvtpk(psB[6], psB[7]) };
    uint4v uB1 = { cvtpk(psB[8], psB[9]),  cvtpk(psB[10], psB[11]),
                   cvtpk(psB[12], psB[13]), cvtpk(psB[14], psB[15]) };
    short8v paA0 = __builtin_bit_cast(short8v, uA0);
    short8v paA1 = __builtin_bit_cast(short8v, uA1);
    short8v paB0 = __builtin_bit_cast(short8v, uB0);
    short8v paB1 = __builtin_bit_cast(short8v, uB1);

    __builtin_amdgcn_s_setprio(1);
    LaccA = __builtin_amdgcn_mfma_f32_16x16x32_bf16(paA0, ones, LaccA, 0, 0, 0);
    LaccA = __builtin_amdgcn_mfma_f32_16x16x32_bf16(paA1, ones, LaccA, 0, 0, 0);
    LaccB = __builtin_amdgcn_mfma_f32_16x16x32_bf16(paB0, ones, LaccB, 0, 0, 0);
    LaccB = __builtin_amdgcn_mfma_f32_16x16x32_bf16(paB1, ones, LaccB, 0, 0, 0);
    // PV both halves: each vb read once, used twice
    #pragma unroll
    for (int nt = 0; nt < 4; ++nt) {
      short8v vb0 = *(const short8v*)&Vc[(nt*16 + lo)*64 + ((hi ^ sw) << 3)];
      short8v vb1 = *(const short8v*)&Vc[(nt*16 + lo)*64 + (((4 + hi) ^ sw) << 3)];
      OaccA[nt] = __builtin_amdgcn_mfma_f32_16x16x32_bf16(paA0, vb0, OaccA[nt], 0,0,0);
      OaccA[nt] = __builtin_amdgcn_mfma_f32_16x16x32_bf16(paA1, vb1, OaccA[nt], 0,0,0);
      OaccB[nt] = __builtin_amdgcn_mfma_f32_16x16x32_bf16(paB0, vb0, OaccB[nt], 0,0,0);
      OaccB[nt] = __builtin_amdgcn_mfma_f32_16x16x32_bf16(paB1, vb1, OaccB[nt], 0,0,0);
    }
    __builtin_amdgcn_s_setprio(0);
    cur = nxt;
    nxt = (nxt == 2) ? 0 : nxt + 1;
  }

  // epilogue: Lacc in Oacc row layout -> rcps only; two 16-row halves
  float invA[4], invB[4];
  #pragma unroll
  for (int r = 0; r < 4; ++r) { invA[r] = 1.f / LaccA[r]; invB[r] = 1.f / LaccB[r]; }
  const int b = bh >> 2, h = bh & 3;
  short* obpA = ob + ((size_t)b * C_ + q0) * L_ + h * D_;
  short* obpB = ob + ((size_t)b * C_ + q0 + 16) * L_ + h * D_;
  #pragma unroll
  for (int nt = 0; nt < 4; ++nt)
    #pragma unroll
    for (int r = 0; r < 4; ++r) {
      obpA[(hi*4 + r) * L_ + nt*16 + lo] = f2bf(OaccA[nt][r] * invA[r]);
      obpB[(hi*4 + r) * L_ + nt*16 + lo] = f2bf(OaccB[nt][r] * invB[r]);
    }
}

// ---- GEMM2 + LN2 + residual, fused (R13-proven). ----
__global__ __launch_bounds__(256, 4) void gemm2_ln_mfma_kernel(
    const short* __restrict__ ob, const short* __restrict__ W2t,
    const float* __restrict__ b2, const float* __restrict__ g2,
    const float* __restrict__ be2, const float* __restrict__ x,
    float* __restrict__ out) {
  __shared__ short As[32*264];
  __shared__ float2 red[4][32];
  __shared__ float mu_s[32], rs_s[32];
  const int tid = threadIdx.x;
  const int w = tid >> 6, l = tid & 63, lo = l & 15, hi = l >> 4;
  const int m0 = blockIdx.x * 32;
  const int nbase = w * 64;

  #pragma unroll
  for (int i = 0; i < 4; ++i) {
    int id = tid + i * 256;
    int row = id >> 5, c8 = (id & 31) * 8;
    *(short8v*)&As[row*264 + c8] =
        *(const short8v*)(ob + (size_t)(m0 + row) * 256 + c8);
  }
  __syncthreads();

  f32x4 acc[2][4];
  #pragma unroll
  for (int m = 0; m < 2; ++m)
    #pragma unroll
    for (int n = 0; n < 4; ++n) acc[m][n] = (f32x4){0.f,0.f,0.f,0.f};

  #pragma unroll
  for (int kt = 0; kt < 4; ++kt)
    #pragma unroll
    for (int kk = 0; kk < 2; ++kk) {
      short8v bf[4];
      #pragma unroll
      for (int n = 0; n < 4; ++n)
        bf[n] = *(const short8v*)(W2t + (size_t)(nbase + n*16 + lo) * 256
                                     + kt*64 + kk*32 + hi*8);
      short8v af0 = *(short8v*)&As[lo*264      + kt*64 + kk*32 + hi*8];
      short8v af1 = *(short8v*)&As[(16+lo)*264 + kt*64 + kk*32 + hi*8];
      #pragma unroll
      for (int n = 0; n < 4; ++n) {
        acc[0][n] = __builtin_amdgcn_mfma_f32_16x16x32_bf16(af0, bf[n], acc[0][n], 0,0,0);
        acc[1][n] = __builtin_amdgcn_mfma_f32_16x16x32_bf16(af1, bf[n], acc[1][n], 0,0,0);
      }
    }

  float bb[4], gg[4], ee[4];
  #pragma unroll
  for (int n = 0; n < 4; ++n) {
    int col = nbase + n*16 + lo;
    bb[n] = b2[col]; gg[n] = g2[col]; ee[n] = be2[col];
  }
  #pragma unroll
  for (int m = 0; m < 2; ++m)
    #pragma unroll
    for (int r = 0; r < 4; ++r) {
      float s = 0.f, s2 = 0.f;
      #pragma unroll
      for (int n = 0; n < 4; ++n) {
        float v = acc[m][n][r] + bb[n];
        acc[m][n][r] = v;
        s += v; s2 += v*v;
      }
      #pragma unroll
      for (int off = 1; off < 16; off <<= 1) {
        s  += __shfl_xor(s, off);
        s2 += __shfl_xor(s2, off);
      }
      if (lo == 0) red[w][m*16 + hi*4 + r] = make_float2(s, s2);
    }
  __syncthreads();
  if (tid < 32) {
    float s = 0.f, s2 = 0.f;
    #pragma unroll
    for (int wv = 0; wv < 4; ++wv) { s += red[wv][tid].x; s2 += red[wv][tid].y; }
    float mu = s * (1.f / L_);
    float var = s2 * (1.f / L_) - mu * mu;
    mu_s[tid] = mu;
    rs_s[tid] = rsqrtf(var + 1e-5f);
  }
  __syncthreads();

  #pragma unroll
  for (int m = 0; m < 2; ++m) {
    float mu4[4], rs4[4];
    #pragma unroll
    for (int r = 0; r < 4; ++r) {
      int row = m*16 + hi*4 + r;
      mu4[r] = mu_s[row]; rs4[r] = rs_s[row];
    }
    #pragma unroll
    for (int r = 0; r < 4; ++r) {
      const int grow = m0 + m*16 + hi*4 + r;
      const float* xr = x + (size_t)grow * L_ + nbase;
      float* orow = out + (size_t)grow * L_ + nbase;
      #pragma unroll
      for (int n = 0; n < 4; ++n)
        orow[n*16 + lo] = (acc[m][n][r] - mu4[r]) * rs4[r] * gg[n] + ee[n]
                        + xr[n*16 + lo];
    }
  }
}

extern "C" void kernel_launch(void* const* d_in, const int* in_sizes, int n_in,
                              void* d_out, int out_size, void* d_ws, size_t ws_size,
                              hipStream_t stream) {
  const float* x   = (const float*)d_in[0];
  const float* W1  = (const float*)d_in[1];
  const float* b1  = (const float*)d_in[2];
  const float* g1  = (const float*)d_in[3];
  const float* be1 = (const float*)d_in[4];
  const float* W2  = (const float*)d_in[5];
  const float* b2  = (const float*)d_in[6];
  const float* g2  = (const float*)d_in[7];
  const float* be2 = (const float*)d_in[8];
  float* out = (float*)d_out;

  const size_t HDSZ = (size_t)B_ * H_ * C_ * D_;   // 4,194,304
  short* W1t = (short*)d_ws;          // [768][256] bf16
  short* W2t = W1t + (size_t)L_ * E_; // [256][256] bf16
  short* Qg  = W2t + (size_t)L_ * L_; // [bh][c][64] (pre-scaled, log2 domain)
  short* Kg  = Qg  + HDSZ;            // [bh][c][64] key-permuted + swizzled
  short* Vtg = Kg  + HDSZ;            // [bh][64][c] swizzled
  short* obm = Vtg + HDSZ;            // [M][256] bf16

  transpose_w_kernel<<<dim3(8, 32), 256, 0, stream>>>(W1, W1t, W2, W2t);
  gemm1_ln_fused_kernel<<<M_ / 64, 512, 0, stream>>>(x, W1t, b1, g1, be1, Qg, Kg, Vtg);
  attn_mfma_kernel<<<dim3(32, C_ / 128), 256, 0, stream>>>(Qg, Kg, Vtg, obm);
  gemm2_ln_mfma_kernel<<<M_ / 32, 256, 0, stream>>>(obm, W2t, b2, g2, be2, x, out);
}

// Round 29
// 86.441 us; speedup vs baseline: 1.0118x; 1.0106x over previous
//
#include <hip/hip_runtime.h>
#include <hip/hip_bf16.h>

#define B_ 8
#define C_ 2048
#define L_ 256
#define E_ 768
#define H_ 4
#define D_ 64
#define M_ (B_*C_)   // 16384 rows

typedef __attribute__((ext_vector_type(8))) short short8v;   // 8 bf16 (4 VGPR) MFMA A/B frag
typedef __attribute__((ext_vector_type(4))) short short4v;   // 8B packed store
typedef __attribute__((ext_vector_type(4))) float f32x4;     // MFMA C/D frag
typedef __attribute__((ext_vector_type(4))) unsigned uint4v;

__device__ __forceinline__ short f2bf(float f) {             // f32 -> bf16 RNE
  union { float f; unsigned u; } v; v.f = f;
  unsigned r = v.u + 0x7FFFu + ((v.u >> 16) & 1u);
  return (short)(r >> 16);
}
// two f32 -> packed bf16x2 in one VALU op (gfx950; no builtin, m240)
__device__ __forceinline__ unsigned cvtpk(float a, float b) {
  unsigned r;
  asm("v_cvt_pk_bf16_f32 %0, %1, %2" : "=v"(r) : "v"(a), "v"(b));
  return r;
}
__device__ __forceinline__ float exp2x(float x) {            // 2^x, single v_exp_f32
  float r;
  asm("v_exp_f32 %0, %1" : "=v"(r) : "v"(x));
  return r;
}

// async global->LDS, 16B per lane; LDS dest = uniform base + lane*16 (m104)
__device__ __forceinline__ void gll16(const void* g, void* l) {
  __builtin_amdgcn_global_load_lds(
      (const __attribute__((address_space(1))) unsigned int*)g,
      (__attribute__((address_space(3))) unsigned int*)l, 16, 0, 0);
}

// ---- prep: W1 f32 [256][768] and W2 f32 [256][256] -> bf16 [N][K] ----
__global__ __launch_bounds__(256) void transpose_w_kernel(
    const float* __restrict__ W1, short* __restrict__ W1t,
    const float* __restrict__ W2, short* __restrict__ W2t) {
  __shared__ float ld[32][33];
  const int isW1 = blockIdx.y < 24;
  const float* W = isW1 ? W1 : W2;
  short* Wt = isW1 ? W1t : W2t;
  const int N = isW1 ? E_ : L_;
  const int k0 = blockIdx.x * 32, n0 = (isW1 ? blockIdx.y : blockIdx.y - 24) * 32;
  const int tx = threadIdx.x & 31, ty = threadIdx.x >> 5;
  #pragma unroll
  for (int j = 0; j < 4; ++j)
    ld[ty + j*8][tx] = W[(size_t)(k0 + ty + j*8) * N + n0 + tx];
  __syncthreads();
  const int r  = threadIdx.x >> 3;
  const int c0 = (threadIdx.x & 7) * 4;
  short4v o;
  o[0]=f2bf(ld[c0+0][r]); o[1]=f2bf(ld[c0+1][r]);
  o[2]=f2bf(ld[c0+2][r]); o[3]=f2bf(ld[c0+3][r]);
  *(short4v*)(Wt + (size_t)(n0 + r) * 256 + k0 + c0) = o;
}

// ---- GEMM1 + LN1 fused (R25-proven): BM=64, Bs double-buffered with
//      counted vmcnt(6); coalesced Q/K epilogue via per-wave LDS transpose. ----
__global__ __launch_bounds__(512, 2) void gemm1_ln_fused_kernel(
    const float* __restrict__ x, const short* __restrict__ W1t,
    const float* __restrict__ b1, const float* __restrict__ g1,
    const float* __restrict__ be1,
    short* __restrict__ Qg, short* __restrict__ Kg, short* __restrict__ Vtg) {
  __shared__ short As[64*264];        // 33.8 KB
  __shared__ short Bs[2][24576];      // 2 x 48 KB per-round B tiles (chunk-swizzled)
  __shared__ short tbuf[8][64][24];   // 24.6 KB per-wave transpose tile
  __shared__ float2 red[8][64];       // 4 KB
  __shared__ float mu_s[64], rs_s[64];
  const int tid = threadIdx.x;
  const int w = tid >> 6, l = tid & 63, lo = l & 15, hi = l >> 4;
  const int m0 = blockIdx.x * 64;
  const int b = m0 >> 11, c0 = m0 & (C_ - 1);
  const int nbase = w * 96;

  // stage A: 64 rows x 256 cols, two 32-row halves
  #pragma unroll
  for (int half = 0; half < 2; ++half) {
    const int row = (tid >> 4) + half * 32, cc = (tid & 15) * 16;
    const float* ap = x + (size_t)(m0 + row) * 256 + cc;
    float4 a0 = ((const float4*)ap)[0], a1 = ((const float4*)ap)[1];
    float4 a2 = ((const float4*)ap)[2], a3 = ((const float4*)ap)[3];
    uint4 p0, p1;
    p0.x = cvtpk(a0.x,a0.y); p0.y = cvtpk(a0.z,a0.w);
    p0.z = cvtpk(a1.x,a1.y); p0.w = cvtpk(a1.z,a1.w);
    p1.x = cvtpk(a2.x,a2.y); p1.y = cvtpk(a2.z,a2.w);
    p1.z = cvtpk(a3.x,a3.y); p1.w = cvtpk(a3.z,a3.w);
    *(uint4*)&As[row*264 + cc]     = p0;
    *(uint4*)&As[row*264 + cc + 8] = p1;
  }

  f32x4 acc[4][6];
  #pragma unroll
  for (int m = 0; m < 4; ++m)
    #pragma unroll
    for (int n = 0; n < 6; ++n) acc[m][n] = (f32x4){0.f,0.f,0.f,0.f};

  // B staging geometry (as R23): issue i covers W1t rows i*128..+127
  const int srowl = l >> 2;
  const int schunk = ((l & 3) ^ (srowl & 3)) << 3;

  // prologue: stage round 0 -> buf 0
  #pragma unroll
  for (int i = 0; i < 6; ++i) {
    const short* src = W1t + (size_t)(i*128 + w*16 + srowl) * 256 + schunk;
    gll16(src, &Bs[0][i*4096 + w*512]);
  }
  __syncthreads();                     // As staged (also pre-loop sync)

  for (int r8 = 0; r8 < 8; ++r8) {
    if (r8) __builtin_amdgcn_s_barrier();   // compute(r8-1) done: buf[(r8+1)&1] free
    if (r8 < 7) {                            // stage round r8+1 -> other buffer
      #pragma unroll
      for (int i = 0; i < 6; ++i) {
        const short* src = W1t + (size_t)(i*128 + w*16 + srowl) * 256
                         + (r8+1)*32 + schunk;
        gll16(src, &Bs[(r8+1)&1][i*4096 + w*512]);
      }
      asm volatile("s_waitcnt vmcnt(6)" ::: "memory");   // round r8's 6 landed
    } else {
      asm volatile("s_waitcnt vmcnt(0)" ::: "memory");
    }
    __builtin_amdgcn_s_barrier();            // all waves' round-r8 DMA complete
    const short* Bc = &Bs[r8&1][0];

    short8v af[4];
    #pragma unroll
    for (int m = 0; m < 4; ++m)
      af[m] = *(short8v*)&As[(m*16 + lo)*264 + r8*32 + hi*8];
    #pragma unroll
    for (int n = 0; n < 6; ++n) {
      const int row = nbase + n*16 + lo;
      short8v bfn = *(const short8v*)&Bc[row*32 + ((hi ^ (lo & 3)) << 3)];
      #pragma unroll
      for (int m = 0; m < 4; ++m)
        acc[m][n] = __builtin_amdgcn_mfma_f32_16x16x32_bf16(af[m], bfn, acc[m][n], 0,0,0);
    }
  }

  float bb[6], ggv[6], eev[6];
  #pragma unroll
  for (int n = 0; n < 6; ++n) {
    int col = nbase + n*16 + lo;
    bb[n] = b1[col]; ggv[n] = g1[col]; eev[n] = be1[col];
  }
  #pragma unroll
  for (int m = 0; m < 4; ++m)
    #pragma unroll
    for (int r = 0; r < 4; ++r) {
      float s = 0.f, s2 = 0.f;
      #pragma unroll
      for (int n = 0; n < 6; ++n) {
        float v = acc[m][n][r] + bb[n];
        acc[m][n][r] = v;
        s += v; s2 += v*v;
      }
      #pragma unroll
      for (int off = 1; off < 16; off <<= 1) {
        s  += __shfl_xor(s, off);
        s2 += __shfl_xor(s2, off);
      }
      if (lo == 0) red[w][m*16 + hi*4 + r] = make_float2(s, s2);
    }
  __syncthreads();
  if (tid < 64) {
    float s = 0.f, s2 = 0.f;
    #pragma unroll
    for (int wv = 0; wv < 8; ++wv) { s += red[wv][tid].x; s2 += red[wv][tid].y; }
    float mu = s * (1.f / E_);
    float var = s2 * (1.f / E_) - mu * mu;
    mu_s[tid] = mu;
    rs_s[tid] = rsqrtf(var + 1e-5f);
  }
  __syncthreads();

  const float qs = 0.18033688011f;    // 0.125 * log2(e)
  float muv[4][4], rsv[4][4];
  #pragma unroll
  for (int m = 0; m < 4; ++m)
    #pragma unroll
    for (int r = 0; r < 4; ++r) {
      int row = m*16 + hi*4 + r;
      muv[m][r] = mu_s[row]; rsv[m][r] = rs_s[row];
    }

  #pragma unroll
  for (int n = 0; n < 6; ++n) {
    const int e0b = nbase + n*16;              // tile base (wave-uniform)
    if (e0b < 512) {                           // Q or K: LDS transpose -> 16B stores
      const float qscale = (e0b < 256) ? qs : 1.f;
      #pragma unroll
      for (int m = 0; m < 4; ++m)
        #pragma unroll
        for (int r = 0; r < 4; ++r) {
          float v = (acc[m][n][r] - muv[m][r]) * rsv[m][r] * ggv[n] + eev[n];
          tbuf[w][m*16 + hi*4 + r][lo] = f2bf(v * qscale);
        }
      // same-wave RAW on tbuf: in-order DS + compiler lgkmcnt
      #pragma unroll
      for (int half = 0; half < 2; ++half) {
        const int trow = (l >> 1) + half * 32, tc = (l & 1) * 8;
        short8v tv = *(short8v*)&tbuf[w][trow][tc];
        const int c = c0 + trow;
        if (e0b < 256) {                       // Q: d-contiguous 16B
          const int h = e0b >> 6, d0 = (e0b & 63) + tc;
          *(short8v*)(Qg + ((size_t)(b*H_ + h) * C_ + c) * D_ + d0) = tv;
        } else {                               // K: full swizzle chunk pair (16B)
          const int eb = e0b - 256, h = eb >> 6, d0 = (eb & 63) + tc;
          int a5 = c & 31;
          int p5 = (((a5 >> 2) & 1) << 4) | (((a5 >> 3) & 3) << 2) | (a5 & 3);
          int cs = (c & ~31) | p5;
          *(short8v*)(Kg + ((size_t)(b*H_ + h) * C_ + cs) * D_
                        + (((d0 >> 3) ^ (cs & 7)) << 3)) = tv;
        }
      }
    } else {                                   // Vt: 8B-contiguous, direct
      const int e0 = e0b + lo;
      const int eb = e0 - 512, h = eb >> 6, d = eb & 63;
      #pragma unroll
      for (int m = 0; m < 4; ++m) {
        short4v pk;
        #pragma unroll
        for (int r = 0; r < 4; ++r)
          pk[r] = f2bf((acc[m][n][r] - muv[m][r]) * rsv[m][r] * ggv[n] + eev[n]);
        const int c = c0 + m*16 + hi*4;
        size_t off = ((size_t)(b*H_ + h) * D_ + d) * C_ + (c & ~63)
                   + ((((c & 63) >> 3) ^ (d & 7)) << 3) + (c & 7);
        *(short4v*)(Vtg + off) = pk;
      }
    }
  }
}

// ---- MFMA flash attention (R17/R25-proven best, 41.5us, 0 bank conflicts):
//      8 waves x 16 q; P in registers via key-permuted K; triple-buffered
//      K/V, single barrier per kt; fixed-ref softmax; l via ones-MFMA. ----
__global__ __launch_bounds__(512, 4) void attn_mfma_kernel(
    const short* __restrict__ Qg, const short* __restrict__ Kg,
    const short* __restrict__ Vtg, short* __restrict__ ob) {
  __shared__ short Ks[3][4096];
  __shared__ short Vs[3][4096];
  const int tid = threadIdx.x;
  const int w  = tid >> 6;
  const int l  = tid & 63, lo = l & 15, hi = l >> 4;
  const int sw = lo & 7;
  const int bh = blockIdx.x, qt = blockIdx.y;
  const size_t hd = (size_t)bh * (C_ * D_);
  const int q0 = qt * 128 + w * 16;

  const short8v bq0 = *(const short8v*)(Qg + hd + (size_t)(q0+lo)*D_ + hi*8);
  const short8v bq1 = *(const short8v*)(Qg + hd + (size_t)(q0+lo)*D_ + 32 + hi*8);

  short8v ones;
  #pragma unroll
  for (int j = 0; j < 8; ++j) ones[j] = (short)0x3F80;

  const short* Ktile = Kg + hd;
  const short* Vrow  = Vtg + hd;
  const int kOff = w*512 + l*8;
  const size_t vOff = (size_t)(w*8 + (l>>3)) * C_ + (l&7)*8;

  f32x4 Oacc[4] = {{0,0,0,0},{0,0,0,0},{0,0,0,0},{0,0,0,0}};
  f32x4 Lacc = {0.f, 0.f, 0.f, 0.f};
  const f32x4 zero4 = {0.f, 0.f, 0.f, 0.f};

  gll16(Ktile + kOff, &Ks[0][w*512]);
  gll16(Vrow + vOff,  &Vs[0][w*512]);

  int cur = 0, nxt = 1;
  for (int kt = 0; kt < 32; ++kt) {
    asm volatile("s_waitcnt vmcnt(0)" ::: "memory");
    __builtin_amdgcn_s_barrier();
    if (kt != 31) {
      const short* kn = Ktile + (size_t)(kt+1) * 4096;
      const short* vn = Vrow  + (size_t)(kt+1) * 64;
      gll16(kn + kOff, &Ks[nxt][w*512]);
      gll16(vn + vOff, &Vs[nxt][w*512]);
    }
    const short* Kc = &Ks[cur][0];
    const short* Vc = &Vs[cur][0];

    f32x4 st[4];
    __builtin_amdgcn_s_setprio(1);
    #pragma unroll
    for (int mt = 0; mt < 4; ++mt) {
      short8v ka = *(const short8v*)&Kc[(mt*16 + lo)*64 + ((hi ^ sw) << 3)];
      short8v kb = *(const short8v*)&Kc[(mt*16 + lo)*64 + (((4 + hi) ^ sw) << 3)];
      f32x4 z = __builtin_amdgcn_mfma_f32_16x16x32_bf16(ka, bq0, zero4, 0, 0, 0);
      st[mt]  = __builtin_amdgcn_mfma_f32_16x16x32_bf16(kb, bq1, z, 0, 0, 0);
    }
    __builtin_amdgcn_s_setprio(0);

    float ps[16];
    #pragma unroll
    for (int mt = 0; mt < 4; ++mt)
      #pragma unroll
      for (int r = 0; r < 4; ++r)
        ps[mt*4 + r] = exp2x(st[mt][r]);
    uint4v up0 = { cvtpk(ps[0], ps[1]),  cvtpk(ps[2], ps[3]),
                   cvtpk(ps[4], ps[5]),  cvtpk(ps[6], ps[7]) };
    uint4v up1 = { cvtpk(ps[8], ps[9]),  cvtpk(ps[10], ps[11]),
                   cvtpk(ps[12], ps[13]), cvtpk(ps[14], ps[15]) };
    short8v pa0 = __builtin_bit_cast(short8v, up0);
    short8v pa1 = __builtin_bit_cast(short8v, up1);

    __builtin_amdgcn_s_setprio(1);
    Lacc = __builtin_amdgcn_mfma_f32_16x16x32_bf16(pa0, ones, Lacc, 0, 0, 0);
    Lacc = __builtin_amdgcn_mfma_f32_16x16x32_bf16(pa1, ones, Lacc, 0, 0, 0);
    #pragma unroll
    for (int nt = 0; nt < 4; ++nt) {
      short8v vb0 = *(const short8v*)&Vc[(nt*16 + lo)*64 + ((hi ^ sw) << 3)];
      short8v vb1 = *(const short8v*)&Vc[(nt*16 + lo)*64 + (((4 + hi) ^ sw) << 3)];
      Oacc[nt] = __builtin_amdgcn_mfma_f32_16x16x32_bf16(pa0, vb0, Oacc[nt], 0,0,0);
      Oacc[nt] = __builtin_amdgcn_mfma_f32_16x16x32_bf16(pa1, vb1, Oacc[nt], 0,0,0);
    }
    __builtin_amdgcn_s_setprio(0);
    cur = nxt;
    nxt = (nxt == 2) ? 0 : nxt + 1;
  }

  float invL[4];
  #pragma unroll
  for (int r = 0; r < 4; ++r) invL[r] = 1.f / Lacc[r];
  const int b = bh >> 2, h = bh & 3;
  short* obp = ob + ((size_t)b * C_ + q0) * L_ + h * D_;
  #pragma unroll
  for (int nt = 0; nt < 4; ++nt)
    #pragma unroll
    for (int r = 0; r < 4; ++r)
      obp[(hi*4 + r) * L_ + nt*16 + lo] = f2bf(Oacc[nt][r] * invL[r]);
}

// ---- GEMM2 + LN2 + residual, fused (R13-proven). ----
__global__ __launch_bounds__(256, 4) void gemm2_ln_mfma_kernel(
    const short* __restrict__ ob, const short* __restrict__ W2t,
    const float* __restrict__ b2, const float* __restrict__ g2,
    const float* __restrict__ be2, const float* __restrict__ x,
    float* __restrict__ out) {
  __shared__ short As[32*264];
  __shared__ float2 red[4][32];
  __shared__ float mu_s[32], rs_s[32];
  const int tid = threadIdx.x;
  const int w = tid >> 6, l = tid & 63, lo = l & 15, hi = l >> 4;
  const int m0 = blockIdx.x * 32;
  const int nbase = w * 64;

  #pragma unroll
  for (int i = 0; i < 4; ++i) {
    int id = tid + i * 256;
    int row = id >> 5, c8 = (id & 31) * 8;
    *(short8v*)&As[row*264 + c8] =
        *(const short8v*)(ob + (size_t)(m0 + row) * 256 + c8);
  }
  __syncthreads();

  f32x4 acc[2][4];
  #pragma unroll
  for (int m = 0; m < 2; ++m)
    #pragma unroll
    for (int n = 0; n < 4; ++n) acc[m][n] = (f32x4){0.f,0.f,0.f,0.f};

  #pragma unroll
  for (int kt = 0; kt < 4; ++kt)
    #pragma unroll
    for (int kk = 0; kk < 2; ++kk) {
      short8v bf[4];
      #pragma unroll
      for (int n = 0; n < 4; ++n)
        bf[n] = *(const short8v*)(W2t + (size_t)(nbase + n*16 + lo) * 256
                                     + kt*64 + kk*32 + hi*8);
      short8v af0 = *(short8v*)&As[lo*264      + kt*64 + kk*32 + hi*8];
      short8v af1 = *(short8v*)&As[(16+lo)*264 + kt*64 + kk*32 + hi*8];
      #pragma unroll
      for (int n = 0; n < 4; ++n) {
        acc[0][n] = __builtin_amdgcn_mfma_f32_16x16x32_bf16(af0, bf[n], acc[0][n], 0,0,0);
        acc[1][n] = __builtin_amdgcn_mfma_f32_16x16x32_bf16(af1, bf[n], acc[1][n], 0,0,0);
      }
    }

  float bb[4], gg[4], ee[4];
  #pragma unroll
  for (int n = 0; n < 4; ++n) {
    int col = nbase + n*16 + lo;
    bb[n] = b2[col]; gg[n] = g2[col]; ee[n] = be2[col];
  }
  #pragma unroll
  for (int m = 0; m < 2; ++m)
    #pragma unroll
    for (int r = 0; r < 4; ++r) {
      float s = 0.f, s2 = 0.f;
      #pragma unroll
      for (int n = 0; n < 4; ++n) {
        float v = acc[m][n][r] + bb[n];
        acc[m][n][r] = v;
        s += v; s2 += v*v;
      }
      #pragma unroll
      for (int off = 1; off < 16; off <<= 1) {
        s  += __shfl_xor(s, off);
        s2 += __shfl_xor(s2, off);
      }
      if (lo == 0) red[w][m*16 + hi*4 + r] = make_float2(s, s2);
    }
  __syncthreads();
  if (tid < 32) {
    float s = 0.f, s2 = 0.f;
    #pragma unroll
    for (int wv = 0; wv < 4; ++wv) { s += red[wv][tid].x; s2 += red[wv][tid].y; }
    float mu = s * (1.f / L_);
    float var = s2 * (1.f / L_) - mu * mu;
    mu_s[tid] = mu;
    rs_s[tid] = rsqrtf(var + 1e-5f);
  }
  __syncthreads();

  #pragma unroll
  for (int m = 0; m < 2; ++m) {
    float mu4[4], rs4[4];
    #pragma unroll
    for (int r = 0; r < 4; ++r) {
      int row = m*16 + hi*4 + r;
      mu4[r] = mu_s[row]; rs4[r] = rs_s[row];
    }
    #pragma unroll
    for (int r = 0; r < 4; ++r) {
      const int grow = m0 + m*16 + hi*4 + r;
      const float* xr = x + (size_t)grow * L_ + nbase;
      float* orow = out + (size_t)grow * L_ + nbase;
      #pragma unroll
      for (int n = 0; n < 4; ++n)
        orow[n*16 + lo] = (acc[m][n][r] - mu4[r]) * rs4[r] * gg[n] + ee[n]
                        + xr[n*16 + lo];
    }
  }
}

extern "C" void kernel_launch(void* const* d_in, const int* in_sizes, int n_in,
                              void* d_out, int out_size, void* d_ws, size_t ws_size,
                              hipStream_t stream) {
  const float* x   = (const float*)d_in[0];
  const float* W1  = (const float*)d_in[1];
  const float* b1  = (const float*)d_in[2];
  const float* g1  = (const float*)d_in[3];
  const float* be1 = (const float*)d_in[4];
  const float* W2  = (const float*)d_in[5];
  const float* b2  = (const float*)d_in[6];
  const float* g2  = (const float*)d_in[7];
  const float* be2 = (const float*)d_in[8];
  float* out = (float*)d_out;

  const size_t HDSZ = (size_t)B_ * H_ * C_ * D_;   // 4,194,304
  short* W1t = (short*)d_ws;          // [768][256] bf16
  short* W2t = W1t + (size_t)L_ * E_; // [256][256] bf16
  short* Qg  = W2t + (size_t)L_ * L_; // [bh][c][64] (pre-scaled, log2 domain)
  short* Kg  = Qg  + HDSZ;            // [bh][c][64] key-permuted + swizzled
  short* Vtg = Kg  + HDSZ;            // [bh][64][c] swizzled
  short* obm = Vtg + HDSZ;            // [M][256] bf16

  transpose_w_kernel<<<dim3(8, 32), 256, 0, stream>>>(W1, W1t, W2, W2t);
  gemm1_ln_fused_kernel<<<M_ / 64, 512, 0, stream>>>(x, W1t, b1, g1, be1, Qg, Kg, Vtg);
  attn_mfma_kernel<<<dim3(32, C_ / 128), 512, 0, stream>>>(Qg, Kg, Vtg, obm);
  gemm2_ln_mfma_kernel<<<M_ / 32, 256, 0, stream>>>(obm, W2t, b2, g2, be2, x, out);
}

// Round 30
// 86.122 us; speedup vs baseline: 1.0155x; 1.0037x over previous
//
#include <hip/hip_runtime.h>
#include <hip/hip_bf16.h>

#define B_ 8
#define C_ 2048
#define L_ 256
#define E_ 768
#define H_ 4
#define D_ 64
#define M_ (B_*C_)   // 16384 rows

typedef __attribute__((ext_vector_type(8))) short short8v;   // 8 bf16 (4 VGPR) MFMA A/B frag
typedef __attribute__((ext_vector_type(4))) short short4v;   // 8B packed store
typedef __attribute__((ext_vector_type(4))) float f32x4;     // MFMA C/D frag
typedef __attribute__((ext_vector_type(4))) unsigned uint4v;

__device__ __forceinline__ short f2bf(float f) {             // f32 -> bf16 RNE
  union { float f; unsigned u; } v; v.f = f;
  unsigned r = v.u + 0x7FFFu + ((v.u >> 16) & 1u);
  return (short)(r >> 16);
}
// two f32 -> packed bf16x2 in one VALU op (gfx950; no builtin, m240)
__device__ __forceinline__ unsigned cvtpk(float a, float b) {
  unsigned r;
  asm("v_cvt_pk_bf16_f32 %0, %1, %2" : "=v"(r) : "v"(a), "v"(b));
  return r;
}
__device__ __forceinline__ float exp2x(float x) {            // 2^x, single v_exp_f32
  float r;
  asm("v_exp_f32 %0, %1" : "=v"(r) : "v"(x));
  return r;
}

// async global->LDS, 16B per lane; LDS dest = uniform base + lane*16 (m104)
__device__ __forceinline__ void gll16(const void* g, void* l) {
  __builtin_amdgcn_global_load_lds(
      (const __attribute__((address_space(1))) unsigned int*)g,
      (__attribute__((address_space(3))) unsigned int*)l, 16, 0, 0);
}

// ---- prep: W1 f32 [256][768] and W2 f32 [256][256] -> bf16 [N][K] ----
__global__ __launch_bounds__(256) void transpose_w_kernel(
    const float* __restrict__ W1, short* __restrict__ W1t,
    const float* __restrict__ W2, short* __restrict__ W2t) {
  __shared__ float ld[32][33];
  const int isW1 = blockIdx.y < 24;
  const float* W = isW1 ? W1 : W2;
  short* Wt = isW1 ? W1t : W2t;
  const int N = isW1 ? E_ : L_;
  const int k0 = blockIdx.x * 32, n0 = (isW1 ? blockIdx.y : blockIdx.y - 24) * 32;
  const int tx = threadIdx.x & 31, ty = threadIdx.x >> 5;
  #pragma unroll
  for (int j = 0; j < 4; ++j)
    ld[ty + j*8][tx] = W[(size_t)(k0 + ty + j*8) * N + n0 + tx];
  __syncthreads();
  const int r  = threadIdx.x >> 3;
  const int c0 = (threadIdx.x & 7) * 4;
  short4v o;
  o[0]=f2bf(ld[c0+0][r]); o[1]=f2bf(ld[c0+1][r]);
  o[2]=f2bf(ld[c0+2][r]); o[3]=f2bf(ld[c0+3][r]);
  *(short4v*)(Wt + (size_t)(n0 + r) * 256 + k0 + c0) = o;
}

// ---- GEMM1 + LN1 fused (R25-proven): BM=64, Bs double-buffered with
//      counted vmcnt(6); coalesced Q/K epilogue via per-wave LDS transpose. ----
__global__ __launch_bounds__(512, 2) void gemm1_ln_fused_kernel(
    const float* __restrict__ x, const short* __restrict__ W1t,
    const float* __restrict__ b1, const float* __restrict__ g1,
    const float* __restrict__ be1,
    short* __restrict__ Qg, short* __restrict__ Kg, short* __restrict__ Vtg) {
  __shared__ short As[64*264];        // 33.8 KB
  __shared__ short Bs[2][24576];      // 2 x 48 KB per-round B tiles (chunk-swizzled)
  __shared__ short tbuf[8][64][24];   // 24.6 KB per-wave transpose tile
  __shared__ float2 red[8][64];       // 4 KB
  __shared__ float mu_s[64], rs_s[64];
  const int tid = threadIdx.x;
  const int w = tid >> 6, l = tid & 63, lo = l & 15, hi = l >> 4;
  const int m0 = blockIdx.x * 64;
  const int b = m0 >> 11, c0 = m0 & (C_ - 1);
  const int nbase = w * 96;

  // stage A: 64 rows x 256 cols, two 32-row halves
  #pragma unroll
  for (int half = 0; half < 2; ++half) {
    const int row = (tid >> 4) + half * 32, cc = (tid & 15) * 16;
    const float* ap = x + (size_t)(m0 + row) * 256 + cc;
    float4 a0 = ((const float4*)ap)[0], a1 = ((const float4*)ap)[1];
    float4 a2 = ((const float4*)ap)[2], a3 = ((const float4*)ap)[3];
    uint4 p0, p1;
    p0.x = cvtpk(a0.x,a0.y); p0.y = cvtpk(a0.z,a0.w);
    p0.z = cvtpk(a1.x,a1.y); p0.w = cvtpk(a1.z,a1.w);
    p1.x = cvtpk(a2.x,a2.y); p1.y = cvtpk(a2.z,a2.w);
    p1.z = cvtpk(a3.x,a3.y); p1.w = cvtpk(a3.z,a3.w);
    *(uint4*)&As[row*264 + cc]     = p0;
    *(uint4*)&As[row*264 + cc + 8] = p1;
  }

  f32x4 acc[4][6];
  #pragma unroll
  for (int m = 0; m < 4; ++m)
    #pragma unroll
    for (int n = 0; n < 6; ++n) acc[m][n] = (f32x4){0.f,0.f,0.f,0.f};

  // B staging geometry (as R23): issue i covers W1t rows i*128..+127
  const int srowl = l >> 2;
  const int schunk = ((l & 3) ^ (srowl & 3)) << 3;

  // prologue: stage round 0 -> buf 0
  #pragma unroll
  for (int i = 0; i < 6; ++i) {
    const short* src = W1t + (size_t)(i*128 + w*16 + srowl) * 256 + schunk;
    gll16(src, &Bs[0][i*4096 + w*512]);
  }
  __syncthreads();                     // As staged (also pre-loop sync)

  for (int r8 = 0; r8 < 8; ++r8) {
    if (r8) __builtin_amdgcn_s_barrier();   // compute(r8-1) done: buf[(r8+1)&1] free
    if (r8 < 7) {                            // stage round r8+1 -> other buffer
      #pragma unroll
      for (int i = 0; i < 6; ++i) {
        const short* src = W1t + (size_t)(i*128 + w*16 + srowl) * 256
                         + (r8+1)*32 + schunk;
        gll16(src, &Bs[(r8+1)&1][i*4096 + w*512]);
      }
      asm volatile("s_waitcnt vmcnt(6)" ::: "memory");   // round r8's 6 landed
    } else {
      asm volatile("s_waitcnt vmcnt(0)" ::: "memory");
    }
    __builtin_amdgcn_s_barrier();            // all waves' round-r8 DMA complete
    const short* Bc = &Bs[r8&1][0];

    short8v af[4];
    #pragma unroll
    for (int m = 0; m < 4; ++m)
      af[m] = *(short8v*)&As[(m*16 + lo)*264 + r8*32 + hi*8];
    #pragma unroll
    for (int n = 0; n < 6; ++n) {
      const int row = nbase + n*16 + lo;
      short8v bfn = *(const short8v*)&Bc[row*32 + ((hi ^ (lo & 3)) << 3)];
      #pragma unroll
      for (int m = 0; m < 4; ++m)
        acc[m][n] = __builtin_amdgcn_mfma_f32_16x16x32_bf16(af[m], bfn, acc[m][n], 0,0,0);
    }
  }

  float bb[6], ggv[6], eev[6];
  #pragma unroll
  for (int n = 0; n < 6; ++n) {
    int col = nbase + n*16 + lo;
    bb[n] = b1[col]; ggv[n] = g1[col]; eev[n] = be1[col];
  }
  #pragma unroll
  for (int m = 0; m < 4; ++m)
    #pragma unroll
    for (int r = 0; r < 4; ++r) {
      float s = 0.f, s2 = 0.f;
      #pragma unroll
      for (int n = 0; n < 6; ++n) {
        float v = acc[m][n][r] + bb[n];
        acc[m][n][r] = v;
        s += v; s2 += v*v;
      }
      #pragma unroll
      for (int off = 1; off < 16; off <<= 1) {
        s  += __shfl_xor(s, off);
        s2 += __shfl_xor(s2, off);
      }
      if (lo == 0) red[w][m*16 + hi*4 + r] = make_float2(s, s2);
    }
  __syncthreads();
  if (tid < 64) {
    float s = 0.f, s2 = 0.f;
    #pragma unroll
    for (int wv = 0; wv < 8; ++wv) { s += red[wv][tid].x; s2 += red[wv][tid].y; }
    float mu = s * (1.f / E_);
    float var = s2 * (1.f / E_) - mu * mu;
    mu_s[tid] = mu;
    rs_s[tid] = rsqrtf(var + 1e-5f);
  }
  __syncthreads();

  const float qs = 0.18033688011f;    // 0.125 * log2(e)
  float muv[4][4], rsv[4][4];
  #pragma unroll
  for (int m = 0; m < 4; ++m)
    #pragma unroll
    for (int r = 0; r < 4; ++r) {
      int row = m*16 + hi*4 + r;
      muv[m][r] = mu_s[row]; rsv[m][r] = rs_s[row];
    }

  #pragma unroll
  for (int n = 0; n < 6; ++n) {
    const int e0b = nbase + n*16;              // tile base (wave-uniform)
    if (e0b < 512) {                           // Q or K: LDS transpose -> 16B stores
      const float qscale = (e0b < 256) ? qs : 1.f;
      #pragma unroll
      for (int m = 0; m < 4; ++m)
        #pragma unroll
        for (int r = 0; r < 4; ++r) {
          float v = (acc[m][n][r] - muv[m][r]) * rsv[m][r] * ggv[n] + eev[n];
          tbuf[w][m*16 + hi*4 + r][lo] = f2bf(v * qscale);
        }
      // same-wave RAW on tbuf: in-order DS + compiler lgkmcnt
      #pragma unroll
      for (int half = 0; half < 2; ++half) {
        const int trow = (l >> 1) + half * 32, tc = (l & 1) * 8;
        short8v tv = *(short8v*)&tbuf[w][trow][tc];
        const int c = c0 + trow;
        if (e0b < 256) {                       // Q: d-contiguous 16B
          const int h = e0b >> 6, d0 = (e0b & 63) + tc;
          *(short8v*)(Qg + ((size_t)(b*H_ + h) * C_ + c) * D_ + d0) = tv;
        } else {                               // K: full swizzle chunk pair (16B)
          const int eb = e0b - 256, h = eb >> 6, d0 = (eb & 63) + tc;
          int a5 = c & 31;
          int p5 = (((a5 >> 2) & 1) << 4) | (((a5 >> 3) & 3) << 2) | (a5 & 3);
          int cs = (c & ~31) | p5;
          *(short8v*)(Kg + ((size_t)(b*H_ + h) * C_ + cs) * D_
                        + (((d0 >> 3) ^ (cs & 7)) << 3)) = tv;
        }
      }
    } else {                                   // Vt: 8B-contiguous, direct
      const int e0 = e0b + lo;
      const int eb = e0 - 512, h = eb >> 6, d = eb & 63;
      #pragma unroll
      for (int m = 0; m < 4; ++m) {
        short4v pk;
        #pragma unroll
        for (int r = 0; r < 4; ++r)
          pk[r] = f2bf((acc[m][n][r] - muv[m][r]) * rsv[m][r] * ggv[n] + eev[n]);
        const int c = c0 + m*16 + hi*4;
        size_t off = ((size_t)(b*H_ + h) * D_ + d) * C_ + (c & ~63)
                   + ((((c & 63) >> 3) ^ (d & 7)) << 3) + (c & 7);
        *(short4v*)(Vtg + off) = pk;
      }
    }
  }
}

// ---- MFMA flash attention (R17/R25-proven best, 41.5us, 0 bank conflicts):
//      8 waves x 16 q; P in registers via key-permuted K; triple-buffered
//      K/V, single barrier per kt; fixed-ref softmax; l via ones-MFMA. ----
__global__ __launch_bounds__(512, 4) void attn_mfma_kernel(
    const short* __restrict__ Qg, const short* __restrict__ Kg,
    const short* __restrict__ Vtg, short* __restrict__ ob) {
  __shared__ short Ks[3][4096];
  __shared__ short Vs[3][4096];
  const int tid = threadIdx.x;
  const int w  = tid >> 6;
  const int l  = tid & 63, lo = l & 15, hi = l >> 4;
  const int sw = lo & 7;
  const int bh = blockIdx.x, qt = blockIdx.y;
  const size_t hd = (size_t)bh * (C_ * D_);
  const int q0 = qt * 128 + w * 16;

  const short8v bq0 = *(const short8v*)(Qg + hd + (size_t)(q0+lo)*D_ + hi*8);
  const short8v bq1 = *(const short8v*)(Qg + hd + (size_t)(q0+lo)*D_ + 32 + hi*8);

  short8v ones;
  #pragma unroll
  for (int j = 0; j < 8; ++j) ones[j] = (short)0x3F80;

  const short* Ktile = Kg + hd;
  const short* Vrow  = Vtg + hd;
  const int kOff = w*512 + l*8;
  const size_t vOff = (size_t)(w*8 + (l>>3)) * C_ + (l&7)*8;

  f32x4 Oacc[4] = {{0,0,0,0},{0,0,0,0},{0,0,0,0},{0,0,0,0}};
  f32x4 Lacc = {0.f, 0.f, 0.f, 0.f};
  const f32x4 zero4 = {0.f, 0.f, 0.f, 0.f};

  gll16(Ktile + kOff, &Ks[0][w*512]);
  gll16(Vrow + vOff,  &Vs[0][w*512]);

  int cur = 0, nxt = 1;
  for (int kt = 0; kt < 32; ++kt) {
    asm volatile("s_waitcnt vmcnt(0)" ::: "memory");
    __builtin_amdgcn_s_barrier();
    if (kt != 31) {
      const short* kn = Ktile + (size_t)(kt+1) * 4096;
      const short* vn = Vrow  + (size_t)(kt+1) * 64;
      gll16(kn + kOff, &Ks[nxt][w*512]);
      gll16(vn + vOff, &Vs[nxt][w*512]);
    }
    const short* Kc = &Ks[cur][0];
    const short* Vc = &Vs[cur][0];

    f32x4 st[4];
    __builtin_amdgcn_s_setprio(1);
    #pragma unroll
    for (int mt = 0; mt < 4; ++mt) {
      short8v ka = *(const short8v*)&Kc[(mt*16 + lo)*64 + ((hi ^ sw) << 3)];
      short8v kb = *(const short8v*)&Kc[(mt*16 + lo)*64 + (((4 + hi) ^ sw) << 3)];
      f32x4 z = __builtin_amdgcn_mfma_f32_16x16x32_bf16(ka, bq0, zero4, 0, 0, 0);
      st[mt]  = __builtin_amdgcn_mfma_f32_16x16x32_bf16(kb, bq1, z, 0, 0, 0);
    }
    __builtin_amdgcn_s_setprio(0);

    float ps[16];
    #pragma unroll
    for (int mt = 0; mt < 4; ++mt)
      #pragma unroll
      for (int r = 0; r < 4; ++r)
        ps[mt*4 + r] = exp2x(st[mt][r]);
    uint4v up0 = { cvtpk(ps[0], ps[1]),  cvtpk(ps[2], ps[3]),
                   cvtpk(ps[4], ps[5]),  cvtpk(ps[6], ps[7]) };
    uint4v up1 = { cvtpk(ps[8], ps[9]),  cvtpk(ps[10], ps[11]),
                   cvtpk(ps[12], ps[13]), cvtpk(ps[14], ps[15]) };
    short8v pa0 = __builtin_bit_cast(short8v, up0);
    short8v pa1 = __builtin_bit_cast(short8v, up1);

    __builtin_amdgcn_s_setprio(1);
    Lacc = __builtin_amdgcn_mfma_f32_16x16x32_bf16(pa0, ones, Lacc, 0, 0, 0);
    Lacc = __builtin_amdgcn_mfma_f32_16x16x32_bf16(pa1, ones, Lacc, 0, 0, 0);
    #pragma unroll
    for (int nt = 0; nt < 4; ++nt) {
      short8v vb0 = *(const short8v*)&Vc[(nt*16 + lo)*64 + ((hi ^ sw) << 3)];
      short8v vb1 = *(const short8v*)&Vc[(nt*16 + lo)*64 + (((4 + hi) ^ sw) << 3)];
      Oacc[nt] = __builtin_amdgcn_mfma_f32_16x16x32_bf16(pa0, vb0, Oacc[nt], 0,0,0);
      Oacc[nt] = __builtin_amdgcn_mfma_f32_16x16x32_bf16(pa1, vb1, Oacc[nt], 0,0,0);
    }
    __builtin_amdgcn_s_setprio(0);
    cur = nxt;
    nxt = (nxt == 2) ? 0 : nxt + 1;
  }

  float invL[4];
  #pragma unroll
  for (int r = 0; r < 4; ++r) invL[r] = 1.f / Lacc[r];
  const int b = bh >> 2, h = bh & 3;
  short* obp = ob + ((size_t)b * C_ + q0) * L_ + h * D_;
  #pragma unroll
  for (int nt = 0; nt < 4; ++nt)
    #pragma unroll
    for (int r = 0; r < 4; ++r)
      obp[(hi*4 + r) * L_ + nt*16 + lo] = f2bf(Oacc[nt][r] * invL[r]);
}

// ---- GEMM2 + LN2 + residual, fused (R13-proven). ----
__global__ __launch_bounds__(256, 4) void gemm2_ln_mfma_kernel(
    const short* __restrict__ ob, const short* __restrict__ W2t,
    const float* __restrict__ b2, const float* __restrict__ g2,
    const float* __restrict__ be2, const float* __restrict__ x,
    float* __restrict__ out) {
  __shared__ short As[32*264];
  __shared__ float2 red[4][32];
  __shared__ float mu_s[32], rs_s[32];
  const int tid = threadIdx.x;
  const int w = tid >> 6, l = tid & 63, lo = l & 15, hi = l >> 4;
  const int m0 = blockIdx.x * 32;
  const int nbase = w * 64;

  #pragma unroll
  for (int i = 0; i < 4; ++i) {
    int id = tid + i * 256;
    int row = id >> 5, c8 = (id & 31) * 8;
    *(short8v*)&As[row*264 + c8] =
        *(const short8v*)(ob + (size_t)(m0 + row) * 256 + c8);
  }
  __syncthreads();

  f32x4 acc[2][4];
  #pragma unroll
  for (int m = 0; m < 2; ++m)
    #pragma unroll
    for (int n = 0; n < 4; ++n) acc[m][n] = (f32x4){0.f,0.f,0.f,0.f};

  #pragma unroll
  for (int kt = 0; kt < 4; ++kt)
    #pragma unroll
    for (int kk = 0; kk < 2; ++kk) {
      short8v bf[4];
      #pragma unroll
      for (int n = 0; n < 4; ++n)
        bf[n] = *(const short8v*)(W2t + (size_t)(nbase + n*16 + lo) * 256
                                     + kt*64 + kk*32 + hi*8);
      short8v af0 = *(short8v*)&As[lo*264      + kt*64 + kk*32 + hi*8];
      short8v af1 = *(short8v*)&As[(16+lo)*264 + kt*64 + kk*32 + hi*8];
      #pragma unroll
      for (int n = 0; n < 4; ++n) {
        acc[0][n] = __builtin_amdgcn_mfma_f32_16x16x32_bf16(af0, bf[n], acc[0][n], 0,0,0);
        acc[1][n] = __builtin_amdgcn_mfma_f32_16x16x32_bf16(af1, bf[n], acc[1][n], 0,0,0);
      }
    }

  float bb[4], gg[4], ee[4];
  #pragma unroll
  for (int n = 0; n < 4; ++n) {
    int col = nbase + n*16 + lo;
    bb[n] = b2[col]; gg[n] = g2[col]; ee[n] = be2[col];
  }
  #pragma unroll
  for (int m = 0; m < 2; ++m)
    #pragma unroll
    for (int r = 0; r < 4; ++r) {
      float s = 0.f, s2 = 0.f;
      #pragma unroll
      for (int n = 0; n < 4; ++n) {
        float v = acc[m][n][r] + bb[n];
        acc[m][n][r] = v;
        s += v; s2 += v*v;
      }
      #pragma unroll
      for (int off = 1; off < 16; off <<= 1) {
        s  += __shfl_xor(s, off);
        s2 += __shfl_xor(s2, off);
      }
      if (lo == 0) red[w][m*16 + hi*4 + r] = make_float2(s, s2);
    }
  __syncthreads();
  if (tid < 32) {
    float s = 0.f, s2 = 0.f;
    #pragma unroll
    for (int wv = 0; wv < 4; ++wv) { s += red[wv][tid].x; s2 += red[wv][tid].y; }
    float mu = s * (1.f / L_);
    float var = s2 * (1.f / L_) - mu * mu;
    mu_s[tid] = mu;
    rs_s[tid] = rsqrtf(var + 1e-5f);
  }
  __syncthreads();

  #pragma unroll
  for (int m = 0; m < 2; ++m) {
    float mu4[4], rs4[4];
    #pragma unroll
    for (int r = 0; r < 4; ++r) {
      int row = m*16 + hi*4 + r;
      mu4[r] = mu_s[row]; rs4[r] = rs_s[row];
    }
    #pragma unroll
    for (int r = 0; r < 4; ++r) {
      const int grow = m0 + m*16 + hi*4 + r;
      const float* xr = x + (size_t)grow * L_ + nbase;
      float* orow = out + (size_t)grow * L_ + nbase;
      #pragma unroll
      for (int n = 0; n < 4; ++n)
        orow[n*16 + lo] = (acc[m][n][r] - mu4[r]) * rs4[r] * gg[n] + ee[n]
                        + xr[n*16 + lo];
    }
  }
}

extern "C" void kernel_launch(void* const* d_in, const int* in_sizes, int n_in,
                              void* d_out, int out_size, void* d_ws, size_t ws_size,
                              hipStream_t stream) {
  const float* x   = (const float*)d_in[0];
  const float* W1  = (const float*)d_in[1];
  const float* b1  = (const float*)d_in[2];
  const float* g1  = (const float*)d_in[3];
  const float* be1 = (const float*)d_in[4];
  const float* W2  = (const float*)d_in[5];
  const float* b2  = (const float*)d_in[6];
  const float* g2  = (const float*)d_in[7];
  const float* be2 = (const float*)d_in[8];
  float* out = (float*)d_out;

  const size_t HDSZ = (size_t)B_ * H_ * C_ * D_;   // 4,194,304
  short* W1t = (short*)d_ws;          // [768][256] bf16
  short* W2t = W1t + (size_t)L_ * E_; // [256][256] bf16
  short* Qg  = W2t + (size_t)L_ * L_; // [bh][c][64] (pre-scaled, log2 domain)
  short* Kg  = Qg  + HDSZ;            // [bh][c][64] key-permuted + swizzled
  short* Vtg = Kg  + HDSZ;            // [bh][64][c] swizzled
  short* obm = Vtg + HDSZ;            // [M][256] bf16

  transpose_w_kernel<<<dim3(8, 32), 256, 0, stream>>>(W1, W1t, W2, W2t);
  gemm1_ln_fused_kernel<<<M_ / 64, 512, 0, stream>>>(x, W1t, b1, g1, be1, Qg, Kg, Vtg);
  attn_mfma_kernel<<<dim3(32, C_ / 128), 512, 0, stream>>>(Qg, Kg, Vtg, obm);
  gemm2_ln_mfma_kernel<<<M_ / 32, 256, 0, stream>>>(obm, W2t, b2, g2, be2, x, out);
}